// Round 1
// baseline (5377.258 us; speedup 1.0000x reference)
//
#include <hip/hip_runtime.h>

typedef _Float16 half8 __attribute__((ext_vector_type(8)));
typedef float floatx4 __attribute__((ext_vector_type(4)));

#define T_STEPS 20
#define NSEQ 131072
#define HID 192
#define ROWS 32
#define HPAD 200            // fp16 elems per LDS h-row; halves 192..194 hold [x.x, x.y, 1]
#define WOFF 147456         // frags: wout section        (3072 halfs)
#define XOFF 150528         // frags: w_ih/bias section   (6144 halfs, compact q==0 layout)
#define FR_TOTAL (XOFF + 6144)

__device__ __forceinline__ float fsig(float x) {
    return __builtin_amdgcn_rcpf(1.f + __builtin_amdgcn_exp2f(-1.4426950408889634f * x));
}
__device__ __forceinline__ float ftanh(float x) {
    return 1.f - 2.f * __builtin_amdgcn_rcpf(__builtin_amdgcn_exp2f(2.8853900817779268f * x) + 1.f);
}

// Rewrite w_hh / w_out / (w_ih,b) into MFMA B-fragment order (fp16).
// B-frag 16x16x32: lane L = q*16 + n holds k = q*8..q*8+7 of column n.
// W_hh section: [12 ht][6 kc][4 g][64 lanes][8 e]  (streamed from L2 every step)
// WX section:   [12 ht][4 g][16 n][8 e] compact — only the q==0 rows (k<8):
//               e0 = w_ih[col][0], e1 = w_ih[col][1], e2 = b_ih[col]+b_hh[col], e3..7 = 0
__global__ void build_frags(const float* __restrict__ whh,
                            const float* __restrict__ wout,
                            const float* __restrict__ wih,
                            const float* __restrict__ bih,
                            const float* __restrict__ bhh,
                            _Float16* __restrict__ dst) {
    int i = blockIdx.x * 256 + threadIdx.x;
    if (i < WOFF) {
        int e = i & 7, L = (i >> 3) & 63, g = (i >> 9) & 3, u = i >> 11;
        int kc = u % 6, ht = u / 6;
        int n = L & 15, q = L >> 4;
        dst[i] = (_Float16)whh[(size_t)(g * HID + ht * 16 + n) * HID + kc * 32 + q * 8 + e];
    } else if (i < XOFF) {
        int k = i - WOFF;
        int e = k & 7, L = (k >> 3) & 63, kc = k >> 9;
        int n = L & 15, q = L >> 4;
        dst[i] = (_Float16)((n < 2) ? wout[n * HID + kc * 32 + q * 8 + e] : 0.f);
    } else if (i < FR_TOTAL) {
        int k = i - XOFF;
        int e = k & 7, n = (k >> 3) & 15, g = (k >> 7) & 3, ht = k >> 9;
        int col = g * HID + ht * 16 + n;
        float v = 0.f;
        if (e == 0)      v = wih[col * 2];
        else if (e == 1) v = wih[col * 2 + 1];
        else if (e == 2) v = bih[col] + bhh[col];
        dst[i] = (_Float16)v;
    }
}

// 768 threads = 12 waves. LDS ~51 KB + VGPR cap 80 (launch_bounds 6 waves/EU)
// -> 2 blocks/CU (24 waves): block A's activation VALU overlaps block B's
// MFMA/load phase. All W_hh K-slices streamed from L2 just-in-time; x + bias
// folded into a 7th MFMA K-slice via hbuf columns 192..194.
__global__ __launch_bounds__(768, 6) void lstm_fused_kernel(
    const float* __restrict__ obs,       // [20][N][2]
    const float* __restrict__ h0,        // [N][192]
    const float* __restrict__ b_out,     // [2]
    const _Float16* __restrict__ frags,  // whh + wout + wx fragments (fp16)
    float* __restrict__ out)             // [20][N][2]
{
    __shared__ _Float16 hbuf[2][ROWS + 1][HPAD];  // 26400 B (row 32 = zero guard)
    __shared__ _Float16 wo_lds[3072];             //  6144 B wout frags
    __shared__ _Float16 wx_lds[6144];             // 12288 B compact x/bias frags
    __shared__ _Float16 wxz[512];                 //  1024 B zero page (quads 1..3)
    __shared__ float2 x_all[T_STEPS][ROWS];       //  5120 B all steps' x

    const int tid  = threadIdx.x;
    const int wave = tid >> 6;
    const int lane = tid & 63;
    const int quad = lane >> 4;
    const int l16  = lane & 15;
    const int ht   = wave;
    const int base = blockIdx.x * ROWS;
    const int j    = ht * 16 + l16;

    // ---- phase A: zero hbuf (incl. pads + guard rows), stage x/wo/wx ----
    const half8 HZ = {0, 0, 0, 0, 0, 0, 0, 0};
    _Float16* hflat = &hbuf[0][0][0];
    for (int i = tid; i < 2 * (ROWS + 1) * HPAD / 8; i += 768)
        *(half8*)&hflat[i * 8] = HZ;
    if (tid < 384)
        *(half8*)&wo_lds[tid * 8] = *(const half8*)&frags[WOFF + tid * 8];
    *(half8*)&wx_lds[tid * 8] = *(const half8*)&frags[XOFF + tid * 8];  // 768*8 = 6144
    if (tid < 64)
        *(half8*)&wxz[tid * 8] = HZ;
    if (tid < T_STEPS * ROWS) {
        int t = tid >> 5, r = tid & 31;
        int src = (t == 0) ? 0 : (t - 1);
        x_all[t][r] = *(const float2*)&obs[((size_t)src * NSEQ + base + r) * 2];
    }
    __syncthreads();

    // ---- phase B: h0 -> hbuf[0] fp16; x_0 and the '1' column ----
    for (int i = tid; i < ROWS * HID / 4; i += 768) {
        float4 v = *(const float4*)&h0[(size_t)base * HID + i * 4];
        int row = (i * 4) / HID, k = (i * 4) - row * HID;
        hbuf[0][row][k]     = (_Float16)v.x;
        hbuf[0][row][k + 1] = (_Float16)v.y;
        hbuf[0][row][k + 2] = (_Float16)v.z;
        hbuf[0][row][k + 3] = (_Float16)v.w;
    }
    if (tid < 64)
        hbuf[0][tid >> 1][192 + (tid & 1)] = (_Float16)((const float*)x_all[0])[tid];
    if (tid < ROWS) {
        hbuf[0][tid][194] = (_Float16)1.f;
        hbuf[1][tid][194] = (_Float16)1.f;
    }
    __syncthreads();

    const float bo_n = (l16 < 2) ? b_out[l16] : 0.f;

    float c[8];
#pragma unroll
    for (int i = 0; i < 8; ++i) c[i] = 0.f;

    // wave-local stream base (W_hh slice for this ht) and hoisted wx pointer
    const _Float16* wgp = frags + (size_t)ht * 12288 + lane * 8;
    const _Float16* wxp = (quad == 0) ? (wx_lds + ht * 512 + l16 * 8) : wxz;

    for (int t = 0; t < T_STEPS; ++t) {
        const _Float16* hb = &hbuf[t & 1][0][0];
        _Float16*       hn = &hbuf[(t + 1) & 1][0][0];

        floatx4 acc[2][4];
#pragma unroll
        for (int rt = 0; rt < 2; ++rt)
#pragma unroll
            for (int g = 0; g < 4; ++g)
                acc[rt][g] = (floatx4){0.f, 0.f, 0.f, 0.f};

        // ---- kc6: x·w_ih + bias via MFMA (A = [x.x,x.y,1,0..] at col 192;
        //      B nonzero only for quad 0 — quads 1..3 read the zero page, so
        //      their over-the-row-end A reads multiply by 0)
#pragma unroll
        for (int g = 0; g < 4; ++g) {
            half8 bx = *(const half8*)(wxp + g * 128);
#pragma unroll
            for (int rt = 0; rt < 2; ++rt) {
                half8 a = *(const half8*)(hb + (rt * 16 + l16) * HPAD + 192 + quad * 8);
                acc[rt][g] = __builtin_amdgcn_mfma_f32_16x16x32_f16(a, bx, acc[rt][g], 0, 0, 0);
            }
        }

        // ---- h @ whh^T: 6 K-slices streamed from L2 (weights stay L2-resident) ----
#pragma unroll
        for (int kc = 0; kc < 6; ++kc) {
            half8 bt[4];
#pragma unroll
            for (int g = 0; g < 4; ++g)
                bt[g] = *(const half8*)(wgp + (kc * 4 + g) * 512);
#pragma unroll
            for (int rt = 0; rt < 2; ++rt) {
                half8 a = *(const half8*)(hb + (rt * 16 + l16) * HPAD + kc * 32 + quad * 8);
#pragma unroll
                for (int g = 0; g < 4; ++g)
                    acc[rt][g] = __builtin_amdgcn_mfma_f32_16x16x32_f16(a, bt[g], acc[rt][g], 0, 0, 0);
            }
        }

        // ---- out_{t-1} = h_t @ w_out.T + b_out (wave 0) ----
        if (ht == 0 && t > 0) {
            const int ot = t - 1;
#pragma unroll
            for (int rt = 0; rt < 2; ++rt) {
                floatx4 ao = {bo_n, bo_n, bo_n, bo_n};
#pragma unroll
                for (int kc = 0; kc < 6; ++kc) {
                    half8 a = *(const half8*)(hb + (rt * 16 + l16) * HPAD + kc * 32 + quad * 8);
                    half8 b = *(const half8*)&wo_lds[kc * 512 + lane * 8];
                    ao = __builtin_amdgcn_mfma_f32_16x16x32_f16(a, b, ao, 0, 0, 0);
                }
                if (l16 < 2) {
#pragma unroll
                    for (int r = 0; r < 4; ++r)
                        out[((size_t)ot * NSEQ + base + rt * 16 + quad * 4 + r) * 2 + l16] = ao[r];
                }
            }
        }

        // ---- activation phase (gates already include x·w_ih + biases) ----
#pragma unroll
        for (int rt = 0; rt < 2; ++rt) {
#pragma unroll
            for (int r = 0; r < 4; ++r) {
                const int row = rt * 16 + quad * 4 + r;
                const int ci = rt * 4 + r;
                const float cn = fsig(acc[rt][1][r]) * c[ci]
                               + fsig(acc[rt][0][r]) * ftanh(acc[rt][2][r]);
                c[ci] = cn;
                hn[row * HPAD + j] = (_Float16)(fsig(acc[rt][3][r]) * ftanh(cn));
            }
        }

        // ---- wave 11: write x_{t+1} into the next buffer (64-lane pattern) ----
        if (ht == 11 && t < T_STEPS - 1)
            hn[(lane >> 1) * HPAD + 192 + (lane & 1)] =
                (_Float16)((const float*)x_all[t + 1])[lane];

        __syncthreads();
    }

    // ---- out_19 from h_20 (in hbuf[0]) ----
    if (ht == 0) {
        const _Float16* hb = &hbuf[0][0][0];
#pragma unroll
        for (int rt = 0; rt < 2; ++rt) {
            floatx4 ao = {bo_n, bo_n, bo_n, bo_n};
#pragma unroll
            for (int kc = 0; kc < 6; ++kc) {
                half8 a = *(const half8*)(hb + (rt * 16 + l16) * HPAD + kc * 32 + quad * 8);
                half8 b = *(const half8*)&wo_lds[kc * 512 + lane * 8];
                ao = __builtin_amdgcn_mfma_f32_16x16x32_f16(a, b, ao, 0, 0, 0);
            }
            if (l16 < 2) {
#pragma unroll
                for (int r = 0; r < 4; ++r)
                    out[((size_t)19 * NSEQ + base + rt * 16 + quad * 4 + r) * 2 + l16] = ao[r];
            }
        }
    }
}

extern "C" void kernel_launch(void* const* d_in, const int* in_sizes, int n_in,
                              void* d_out, int out_size, void* d_ws, size_t ws_size,
                              hipStream_t stream) {
    const float* obs  = (const float*)d_in[0];
    const float* h0   = (const float*)d_in[1];
    const float* wih  = (const float*)d_in[2];
    const float* whh  = (const float*)d_in[3];
    const float* bih  = (const float*)d_in[4];
    const float* bhh  = (const float*)d_in[5];
    const float* wout = (const float*)d_in[6];
    const float* bout = (const float*)d_in[7];
    float* out = (float*)d_out;
    _Float16* frags = (_Float16*)d_ws;   // 313344 B used

    build_frags<<<(FR_TOTAL + 255) / 256, 256, 0, stream>>>(whh, wout, wih, bih, bhh, frags);
    lstm_fused_kernel<<<NSEQ / ROWS, 768, 0, stream>>>(obs, h0, bout, frags, out);
}

// Round 2
// 1290.704 us; speedup vs baseline: 4.1661x; 4.1661x over previous
//
#include <hip/hip_runtime.h>

typedef _Float16 half8 __attribute__((ext_vector_type(8)));
typedef float floatx4 __attribute__((ext_vector_type(4)));

#define T_STEPS 20
#define NSEQ 131072
#define HID 192
#define ROWS 32
#define HPAD 200            // fp16 elems per LDS h-row; cols 192..194 = [x.x, x.y, 1]
#define HROWS 17            // 16 rows + zero guard row (kc6 quad over-read)
#define WOFF 147456         // frags: wout section      (3072 halfs)
#define XOFF 150528         // frags: w_ih/bias section (6144 halfs, compact q==0 layout)
#define FR_TOTAL (XOFF + 6144)

__device__ __forceinline__ float fsig(float x) {
    return __builtin_amdgcn_rcpf(1.f + __builtin_amdgcn_exp2f(-1.4426950408889634f * x));
}
__device__ __forceinline__ float ftanh(float x) {
    return 1.f - 2.f * __builtin_amdgcn_rcpf(__builtin_amdgcn_exp2f(2.8853900817779268f * x) + 1.f);
}

// Rewrite w_hh / w_out / (w_ih,b) into MFMA B-fragment order (fp16).
// B-frag 16x16x32: lane L = q*16 + n holds k = q*8..q*8+7 of column n.
// W_hh section: [12 ht][6 kc][4 g][64 lanes][8 e]
// WX section:   [12 ht][4 g][16 n][8 e] compact — only the q==0 rows (k<8):
//               e0 = w_ih[col][0], e1 = w_ih[col][1], e2 = b_ih[col]+b_hh[col], e3..7 = 0
__global__ void build_frags(const float* __restrict__ whh,
                            const float* __restrict__ wout,
                            const float* __restrict__ wih,
                            const float* __restrict__ bih,
                            const float* __restrict__ bhh,
                            _Float16* __restrict__ dst) {
    int i = blockIdx.x * 256 + threadIdx.x;
    if (i < WOFF) {
        int e = i & 7, L = (i >> 3) & 63, g = (i >> 9) & 3, u = i >> 11;
        int kc = u % 6, ht = u / 6;
        int n = L & 15, q = L >> 4;
        dst[i] = (_Float16)whh[(size_t)(g * HID + ht * 16 + n) * HID + kc * 32 + q * 8 + e];
    } else if (i < XOFF) {
        int k = i - WOFF;
        int e = k & 7, L = (k >> 3) & 63, kc = k >> 9;
        int n = L & 15, q = L >> 4;
        dst[i] = (_Float16)((n < 2) ? wout[n * HID + kc * 32 + q * 8 + e] : 0.f);
    } else if (i < FR_TOTAL) {
        int k = i - XOFF;
        int e = k & 7, n = (k >> 3) & 15, g = (k >> 7) & 3, ht = k >> 9;
        int col = g * HID + ht * 16 + n;
        float v = 0.f;
        if (e == 0)      v = wih[col * 2];
        else if (e == 1) v = wih[col * 2 + 1];
        else if (e == 2) v = bih[col] + bhh[col];
        dst[i] = (_Float16)v;
    }
}

// 768 threads = 12 waves, 1 block/CU (LDS 143 KB). Skewed two-half schedule:
// each segment ISSUES one half's MFMAs (matrix pipe) and RUNS the other
// half's activation VALU on the previous segment's accumulator, so the
// MFMA pipe drains under the transcendental stretch. No global loads in
// the loop: whh kc0-3 resident in VGPRs, kc4-5 in LDS, x/bias folded as
// a 7th MFMA K-slice (cols 192..194 of the h rows).
__global__ __launch_bounds__(768, 3) void lstm_fused_kernel(
    const float* __restrict__ obs,       // [20][N][2]
    const float* __restrict__ h0,        // [N][192]
    const float* __restrict__ b_out,     // [2]
    const _Float16* __restrict__ frags,  // whh + wout + wx fragments (fp16)
    float* __restrict__ out)             // [20][N][2]
{
    __shared__ _Float16 h0b[2][HROWS][HPAD];  // rows 0..15, double-buffered (13600 B)
    __shared__ _Float16 h1b[HROWS][HPAD];     // rows 16..31, single-buffered (6800 B)
    __shared__ _Float16 b_lds[49152];         // whh kc4,kc5: [12ht][2][4g][512] (98304 B)
    __shared__ _Float16 wo_lds[3072];         // wout frags (6144 B)
    __shared__ _Float16 wx_lds[6144];         // compact x/bias frags (12288 B)
    __shared__ _Float16 wxz[512];             // zero page for quads 1..3 (1024 B)
    __shared__ float2 x_all[T_STEPS][ROWS];   // all steps' x (5120 B)

    const int tid  = threadIdx.x;
    const int wave = tid >> 6;
    const int lane = tid & 63;
    const int quad = lane >> 4;
    const int l16  = lane & 15;
    const int ht   = wave;
    const int base = blockIdx.x * ROWS;
    const int j    = ht * 16 + l16;

    // ---- resident weights: whh kc0..3 B-frags (64 VGPRs), loaded once ----
    half8 bw[16];
#pragma unroll
    for (int kc = 0; kc < 4; ++kc)
#pragma unroll
        for (int g = 0; g < 4; ++g)
            bw[kc * 4 + g] = *(const half8*)&frags[(((ht * 6 + kc) * 4 + g) << 9) + lane * 8];

    // ---- staging phase A: zero h-buffers, stage weight/x LDS ----
    const half8 HZ = {0, 0, 0, 0, 0, 0, 0, 0};
    for (int i = tid; i < 2 * HROWS * HPAD / 8; i += 768) ((half8*)h0b)[i] = HZ;
    for (int i = tid; i < HROWS * HPAD / 8; i += 768)     ((half8*)h1b)[i] = HZ;
    for (int i = tid; i < 6144; i += 768) {   // b_lds <- whh kc4,kc5
        int g = (i >> 6) & 3, u = i >> 8, k2 = u & 1, h = u >> 1;
        ((half8*)b_lds)[i] = *(const half8*)&frags[(((h * 6 + 4 + k2) * 4 + g) << 9) + (i & 63) * 8];
    }
    if (tid < 384) ((half8*)wo_lds)[tid] = *(const half8*)&frags[WOFF + tid * 8];
    ((half8*)wx_lds)[tid] = *(const half8*)&frags[XOFF + tid * 8];   // 768*8 = 6144
    if (tid < 64) ((half8*)wxz)[tid] = HZ;
    if (tid < T_STEPS * ROWS) {
        int t = tid >> 5, r = tid & 31;
        int src = (t == 0) ? 0 : (t - 1);
        x_all[t][r] = *(const float2*)&obs[((size_t)src * NSEQ + base + r) * 2];
    }
    __syncthreads();

    // ---- staging phase B: h0 -> fp16 rows; x_0; the '1' column ----
    for (int i = tid; i < ROWS * HID / 4; i += 768) {
        float4 v = *(const float4*)&h0[(size_t)base * HID + i * 4];
        int row = (i * 4) / HID, k = i * 4 - row * HID;
        _Float16* d = (row < 16) ? &h0b[0][row][k] : &h1b[row - 16][k];
        d[0] = (_Float16)v.x; d[1] = (_Float16)v.y;
        d[2] = (_Float16)v.z; d[3] = (_Float16)v.w;
    }
    if (tid < 64) {
        int row = tid >> 1;
        _Float16 v = (_Float16)((const float*)x_all[0])[tid];
        if (row < 16) h0b[0][row][192 + (tid & 1)] = v;
        else          h1b[row - 16][192 + (tid & 1)] = v;
    }
    if (tid < 16)      { h0b[0][tid][194] = (_Float16)1.f; h0b[1][tid][194] = (_Float16)1.f; }
    else if (tid < 32)   h1b[tid - 16][194] = (_Float16)1.f;
    __syncthreads();

    const float bo_n = (l16 < 2) ? b_out[l16] : 0.f;
    const _Float16* wxp = (quad == 0) ? (wx_lds + ht * 512 + l16 * 8) : wxz;

    float c[8];
#pragma unroll
    for (int i = 0; i < 8; ++i) c[i] = 0.f;

    // full gate MFMA for one 16-row half: kc6 (x/bias) + kc0..3 (regs) + kc4..5 (LDS)
    auto run_mfma = [&](const _Float16* hb, floatx4* acc) {
        const _Float16* ar = hb + l16 * HPAD;
        half8 ax = *(const half8*)(ar + 192 + quad * 8);  // quads 1-3 over-read: B=0
#pragma unroll
        for (int g = 0; g < 4; ++g) {
            half8 bxg = *(const half8*)(wxp + g * 128);
            acc[g] = __builtin_amdgcn_mfma_f32_16x16x32_f16(ax, bxg, acc[g], 0, 0, 0);
        }
#pragma unroll
        for (int kc = 0; kc < 4; ++kc) {
            half8 a = *(const half8*)(ar + kc * 32 + quad * 8);
#pragma unroll
            for (int g = 0; g < 4; ++g)
                acc[g] = __builtin_amdgcn_mfma_f32_16x16x32_f16(a, bw[kc * 4 + g], acc[g], 0, 0, 0);
        }
#pragma unroll
        for (int k2 = 0; k2 < 2; ++k2) {
            half8 a = *(const half8*)(ar + (4 + k2) * 32 + quad * 8);
#pragma unroll
            for (int g = 0; g < 4; ++g) {
                half8 b = *(const half8*)&b_lds[(((ht * 2 + k2) * 4 + g) << 9) + lane * 8];
                acc[g] = __builtin_amdgcn_mfma_f32_16x16x32_f16(a, b, acc[g], 0, 0, 0);
            }
        }
    };

    auto activation = [&](floatx4* acc, _Float16* hw, int cb) {
#pragma unroll
        for (int r = 0; r < 4; ++r) {
            const int row = quad * 4 + r;
            const float cn = fsig(acc[1][r]) * c[cb + r]
                           + fsig(acc[0][r]) * ftanh(acc[2][r]);
            c[cb + r] = cn;
            hw[row * HPAD + j] = (_Float16)(fsig(acc[3][r]) * ftanh(cn));
        }
    };

    auto run_wout = [&](int ot, const _Float16* hbl, const _Float16* hbh) {
#pragma unroll
        for (int rt = 0; rt < 2; ++rt) {
            const _Float16* ar = ((rt == 0) ? hbl : hbh) + l16 * HPAD;
            floatx4 ao = {bo_n, bo_n, bo_n, bo_n};
#pragma unroll
            for (int kc = 0; kc < 6; ++kc) {
                half8 a = *(const half8*)(ar + kc * 32 + quad * 8);
                half8 b = *(const half8*)&wo_lds[kc * 512 + lane * 8];
                ao = __builtin_amdgcn_mfma_f32_16x16x32_f16(a, b, ao, 0, 0, 0);
            }
            if (l16 < 2) {
#pragma unroll
                for (int r = 0; r < 4; ++r)
                    out[((size_t)ot * NSEQ + base + rt * 16 + quad * 4 + r) * 2 + l16] = ao[r];
            }
        }
    };

    // ---- prologue: accA = gates for half0 at t=0 ----
    floatx4 accA[4], accB[4];
#pragma unroll
    for (int g = 0; g < 4; ++g) accA[g] = (floatx4){0.f, 0.f, 0.f, 0.f};
    run_mfma(&h0b[0][0][0], accA);

    for (int t = 0; t < T_STEPS; ++t) {
        // ================= Segment X =================
        // issue H1 MFMAs (reads h1b = S_t rows 16..31)
#pragma unroll
        for (int g = 0; g < 4; ++g) accB[g] = (floatx4){0.f, 0.f, 0.f, 0.f};
        run_mfma(&h1b[0][0], accB);
        // out[t-1] from S_t (h0b[t&1] stable this segment, h1b stable this segment)
        if (ht == 0 && t > 0)
            run_wout(t - 1, &h0b[t & 1][0][0], &h1b[0][0]);
        // activation for half0: consumes accA (issued last segment), writes S_{t+1} H0
        activation(accA, &h0b[(t + 1) & 1][0][0], 0);
        // x_{t+1} into the buffer MFMA-H0 will read next segment
        if (ht == 11 && lane < 32 && t < T_STEPS - 1)
            h0b[(t + 1) & 1][lane >> 1][192 + (lane & 1)] =
                (_Float16)((const float*)x_all[t + 1])[lane];
        __syncthreads();

        // ================= Segment Y =================
        // issue H0 MFMAs for step t+1 (reads h0b[(t+1)&1], just written)
        if (t < T_STEPS - 1) {
#pragma unroll
            for (int g = 0; g < 4; ++g) accA[g] = (floatx4){0.f, 0.f, 0.f, 0.f};
            run_mfma(&h0b[(t + 1) & 1][0][0], accA);
        }
        // activation for half1: consumes accB, writes S_{t+1} H1 (h1b)
        activation(accB, &h1b[0][0], 4);
        if (ht == 11 && lane < 32 && t < T_STEPS - 1)
            h1b[lane >> 1][192 + (lane & 1)] =
                (_Float16)((const float*)x_all[t + 1])[32 + lane];
        __syncthreads();
    }

    // ---- out_19 from S_20 (h0b[0] + h1b) ----
    if (ht == 0)
        run_wout(T_STEPS - 1, &h0b[0][0][0], &h1b[0][0]);
}

extern "C" void kernel_launch(void* const* d_in, const int* in_sizes, int n_in,
                              void* d_out, int out_size, void* d_ws, size_t ws_size,
                              hipStream_t stream) {
    const float* obs  = (const float*)d_in[0];
    const float* h0   = (const float*)d_in[1];
    const float* wih  = (const float*)d_in[2];
    const float* whh  = (const float*)d_in[3];
    const float* bih  = (const float*)d_in[4];
    const float* bhh  = (const float*)d_in[5];
    const float* wout = (const float*)d_in[6];
    const float* bout = (const float*)d_in[7];
    float* out = (float*)d_out;
    _Float16* frags = (_Float16*)d_ws;   // 313344 B used

    build_frags<<<(FR_TOTAL + 255) / 256, 256, 0, stream>>>(whh, wout, wih, bih, bhh, frags);
    lstm_fused_kernel<<<NSEQ / ROWS, 768, 0, stream>>>(obs, h0, bout, frags, out);
}

// Round 3
// 1189.606 us; speedup vs baseline: 4.5202x; 1.0850x over previous
//
#include <hip/hip_runtime.h>

typedef _Float16 half8 __attribute__((ext_vector_type(8)));
typedef float floatx4 __attribute__((ext_vector_type(4)));

#define T_STEPS 20
#define NSEQ 131072
#define HID 192
#define ROWS 32
#define HPAD 200            // fp16 elems per LDS h-row; cols 192..194 = [x.x, x.y, 1]
#define HROWS 17            // 16 rows + zero guard row (kc6 quad over-read)
#define WOFF 147456         // frags: wout section      (3072 halfs)
#define XOFF 150528         // frags: w_ih/bias section (6144 halfs, compact q==0 layout)
#define FR_TOTAL (XOFF + 6144)

#define MFMA16(a, b, c) __builtin_amdgcn_mfma_f32_16x16x32_f16((a), (b), (c), 0, 0, 0)

// Rewrite w_hh / w_out / (w_ih,b) into MFMA B-fragment order (fp16).
// B-frag 16x16x32: lane L = q*16 + n holds k = q*8..q*8+7 of column n.
// W_hh section: [12 ht][6 kc][4 g][64 lanes][8 e]
// WX section:   [12 ht][4 g][16 n][8 e] compact — only the q==0 rows (k<8):
//               e0 = w_ih[col][0], e1 = w_ih[col][1], e2 = b_ih[col]+b_hh[col], e3..7 = 0
__global__ void build_frags(const float* __restrict__ whh,
                            const float* __restrict__ wout,
                            const float* __restrict__ wih,
                            const float* __restrict__ bih,
                            const float* __restrict__ bhh,
                            _Float16* __restrict__ dst) {
    int i = blockIdx.x * 256 + threadIdx.x;
    if (i < WOFF) {
        int e = i & 7, L = (i >> 3) & 63, g = (i >> 9) & 3, u = i >> 11;
        int kc = u % 6, ht = u / 6;
        int n = L & 15, q = L >> 4;
        dst[i] = (_Float16)whh[(size_t)(g * HID + ht * 16 + n) * HID + kc * 32 + q * 8 + e];
    } else if (i < XOFF) {
        int k = i - WOFF;
        int e = k & 7, L = (k >> 3) & 63, kc = k >> 9;
        int n = L & 15, q = L >> 4;
        dst[i] = (_Float16)((n < 2) ? wout[n * HID + kc * 32 + q * 8 + e] : 0.f);
    } else if (i < FR_TOTAL) {
        int k = i - XOFF;
        int e = k & 7, n = (k >> 3) & 15, g = (k >> 7) & 3, ht = k >> 9;
        int col = g * HID + ht * 16 + n;
        float v = 0.f;
        if (e == 0)      v = wih[col * 2];
        else if (e == 1) v = wih[col * 2 + 1];
        else if (e == 2) v = bih[col] + bhh[col];
        dst[i] = (_Float16)v;
    }
}

// 768 threads = 12 waves, 1 block/CU (LDS ~130 KB). Skewed two-half schedule
// with INSTRUCTION-LEVEL interleave: each segment's MFMA issue (next half's
// gates) is interleaved with the previous half's activation VALU via
// sched_group_barrier, so matrix and VALU pipes run concurrently.
// amdgpu_waves_per_eu(3,3) gives the allocator the true 3-wave/EU budget
// (round-2's launch_bounds min-only caused a ~15-reg phantom spill: 203 MB
// of scratch WRITE_SIZE).
__global__ __launch_bounds__(768) __attribute__((amdgpu_waves_per_eu(3, 3)))
void lstm_fused_kernel(
    const float* __restrict__ obs,       // [20][N][2]
    const float* __restrict__ h0,        // [N][192]
    const float* __restrict__ b_out,     // [2]
    const _Float16* __restrict__ frags,  // whh + wout + wx fragments (fp16)
    float* __restrict__ out)             // [20][N][2]
{
    __shared__ _Float16 h0b[2][HROWS][HPAD];  // rows 0..15, double-buffered (13600 B)
    __shared__ _Float16 h1b[HROWS][HPAD];     // rows 16..31, single-buffered (6800 B)
    __shared__ _Float16 b_lds[49152];         // whh kc4,kc5: [12ht][2][4g][512] (98304 B)
    __shared__ _Float16 wo_lds[3072];         // wout frags (6144 B)
    __shared__ float2 x_all[T_STEPS][ROWS];   // all steps' x (5120 B)

    const int tid  = threadIdx.x;
    const int wave = tid >> 6;
    const int lane = tid & 63;
    const int quad = lane >> 4;
    const int l16  = lane & 15;
    const int ht   = wave;
    const int base = blockIdx.x * ROWS;
    const int j    = ht * 16 + l16;

    const half8 HZ = {0, 0, 0, 0, 0, 0, 0, 0};

    // ---- resident weights: whh kc0..3 B-frags (64 VGPRs) + kc6 x/bias (16) ----
    half8 bw[16], bx[4];
#pragma unroll
    for (int kc = 0; kc < 4; ++kc)
#pragma unroll
        for (int g = 0; g < 4; ++g)
            bw[kc * 4 + g] = *(const half8*)&frags[(((ht * 6 + kc) * 4 + g) << 9) + lane * 8];
#pragma unroll
    for (int g = 0; g < 4; ++g)
        bx[g] = (quad == 0)
              ? *(const half8*)&frags[XOFF + ht * 512 + g * 128 + l16 * 8]
              : HZ;   // quads 1..3 contribute zero (their A over-read is nulled)

    // ---- staging phase A: zero h-buffers, stage kc4-5 / wout / x ----
    for (int i = tid; i < 2 * HROWS * HPAD / 8; i += 768) ((half8*)h0b)[i] = HZ;
    for (int i = tid; i < HROWS * HPAD / 8; i += 768)     ((half8*)h1b)[i] = HZ;
    for (int i = tid; i < 6144; i += 768) {   // b_lds <- whh kc4,kc5
        int g = (i >> 6) & 3, u = i >> 8, k2 = u & 1, h = u >> 1;
        ((half8*)b_lds)[i] = *(const half8*)&frags[(((h * 6 + 4 + k2) * 4 + g) << 9) + (i & 63) * 8];
    }
    if (tid < 384) ((half8*)wo_lds)[tid] = *(const half8*)&frags[WOFF + tid * 8];
    if (tid < T_STEPS * ROWS) {
        int t = tid >> 5, r = tid & 31;
        int src = (t == 0) ? 0 : (t - 1);
        x_all[t][r] = *(const float2*)&obs[((size_t)src * NSEQ + base + r) * 2];
    }
    __syncthreads();

    // ---- staging phase B: h0 -> fp16 rows; x_0; the '1' column ----
    for (int i = tid; i < ROWS * HID / 4; i += 768) {
        float4 v = *(const float4*)&h0[(size_t)base * HID + i * 4];
        int row = (i * 4) / HID, k = i * 4 - row * HID;
        _Float16* d = (row < 16) ? &h0b[0][row][k] : &h1b[row - 16][k];
        d[0] = (_Float16)v.x; d[1] = (_Float16)v.y;
        d[2] = (_Float16)v.z; d[3] = (_Float16)v.w;
    }
    if (tid < 64) {
        int row = tid >> 1;
        _Float16 v = (_Float16)((const float*)x_all[0])[tid];
        if (row < 16) h0b[0][row][192 + (tid & 1)] = v;
        else          h1b[row - 16][192 + (tid & 1)] = v;
    }
    if (tid < 16)      { h0b[0][tid][194] = (_Float16)1.f; h0b[1][tid][194] = (_Float16)1.f; }
    else if (tid < 32)   h1b[tid - 16][194] = (_Float16)1.f;
    __syncthreads();

    const float bo_n = (l16 < 2) ? b_out[l16] : 0.f;

    float c[8];
#pragma unroll
    for (int i = 0; i < 8; ++i) c[i] = 0.f;

    // gate MFMAs for one 16-row half: kc6 (regs) + kc0..3 (regs) + kc4..5 (LDS)
    auto build = [&](const _Float16* hb, floatx4* aN) {
        const _Float16* ar = hb + l16 * HPAD;
        const _Float16* blp = b_lds;
        asm volatile("" : "+v"(blp));     // defeat LICM of the b-frag ds_reads
#pragma unroll
        for (int g = 0; g < 4; ++g) aN[g] = (floatx4){0.f, 0.f, 0.f, 0.f};
        half8 ax = *(const half8*)(ar + 192 + quad * 8);   // quads 1-3 over-read: B=0
#pragma unroll
        for (int g = 0; g < 4; ++g)
            aN[g] = MFMA16(ax, bx[g], aN[g]);
#pragma unroll
        for (int kc = 0; kc < 4; ++kc) {
            half8 a = *(const half8*)(ar + kc * 32 + quad * 8);
#pragma unroll
            for (int g = 0; g < 4; ++g)
                aN[g] = MFMA16(a, bw[kc * 4 + g], aN[g]);
        }
#pragma unroll
        for (int k2 = 0; k2 < 2; ++k2) {
            half8 a = *(const half8*)(ar + (4 + k2) * 32 + quad * 8);
#pragma unroll
            for (int g = 0; g < 4; ++g) {
                half8 b = *(const half8*)&blp[(((ht * 2 + k2) * 4 + g) << 9) + lane * 8];
                aN[g] = MFMA16(a, b, aN[g]);
            }
        }
    };

    // activation (trans-reduced: 5 exp + 2 rcp per cell, rational form)
    auto act = [&](floatx4* aO, _Float16* hw, int cb) {
#pragma unroll
        for (int r = 0; r < 4; ++r) {
            const int row = quad * 4 + r;
            const float Ai = __builtin_amdgcn_exp2f(-1.4426950408889634f * aO[0][r]);
            const float Af = __builtin_amdgcn_exp2f(-1.4426950408889634f * aO[1][r]);
            const float Bg = __builtin_amdgcn_exp2f( 2.8853900817779268f * aO[2][r]);
            const float Co = __builtin_amdgcn_exp2f(-1.4426950408889634f * aO[3][r]);
            const float Qf = 1.f + Af;
            const float Pg = (1.f + Ai) * (Bg + 1.f);
            const float Nn = c[cb + r] * Pg + Qf * (Bg - 1.f);
            const float cn = Nn * __builtin_amdgcn_rcpf(Qf * Pg);
            c[cb + r] = cn;
            const float Dc = __builtin_amdgcn_exp2f(2.8853900817779268f * cn);
            const float hv = (Dc - 1.f) * __builtin_amdgcn_rcpf((1.f + Co) * (Dc + 1.f));
            hw[row * HPAD + j] = (_Float16)hv;
        }
    };

    // T19 pin: per segment 7x {2 DS_READ, 4 MFMA, 16 VALU} + 4 DS_WRITE.
    // avail per segment: 15 ds_read_b128, 28 MFMA, ~125 VALU, 4 ds_write.
    auto sched_pattern = [&]() {
#pragma unroll
        for (int u = 0; u < 7; ++u) {
            __builtin_amdgcn_sched_group_barrier(0x100, 2, 0);   // DS_READ
            __builtin_amdgcn_sched_group_barrier(0x008, 4, 0);   // MFMA
            __builtin_amdgcn_sched_group_barrier(0x002, 16, 0);  // VALU
        }
        __builtin_amdgcn_sched_group_barrier(0x200, 4, 0);       // DS_WRITE (h)
    };

    // wout for one 16-row half (wave 0 -> rows 0..15, wave 1 -> rows 16..31)
    auto wout1 = [&](int ot, const _Float16* hbase) {
        const _Float16* ar = hbase + l16 * HPAD;
        floatx4 ao = {bo_n, bo_n, bo_n, bo_n};
#pragma unroll
        for (int kc = 0; kc < 6; ++kc) {
            half8 a = *(const half8*)(ar + kc * 32 + quad * 8);
            half8 b = *(const half8*)&wo_lds[kc * 512 + lane * 8];
            ao = MFMA16(a, b, ao);
        }
        if (l16 < 2) {
#pragma unroll
            for (int r = 0; r < 4; ++r)
                out[((size_t)ot * NSEQ + base + ht * 16 + quad * 4 + r) * 2 + l16] = ao[r];
        }
    };

    // ---- prologue: accA = gates for half0 at t=0 ----
    floatx4 accA[4], accB[4];
    build(&h0b[0][0][0], accA);

    for (int t = 0; t < T_STEPS - 1; ++t) {
        _Float16* h0n = &h0b[(t + 1) & 1][0][0];

        // ===== segment X: issue H1 gate MFMAs || activation(accA) -> next H0 =====
        build(&h1b[0][0], accB);
        act(accA, h0n, 0);
        sched_pattern();
        if (ht < 2 && t > 0)
            wout1(t - 1, (ht == 0) ? &h0b[t & 1][0][0] : &h1b[0][0]);
        if (ht == 11 && lane < 32)
            h0n[(lane >> 1) * HPAD + 192 + (lane & 1)] =
                (_Float16)((const float*)x_all[t + 1])[lane];
        __syncthreads();

        // ===== segment Y: issue next-H0 gate MFMAs || activation(accB) -> H1 =====
        build(h0n, accA);
        act(accB, &h1b[0][0], 4);
        sched_pattern();
        if (ht == 11 && lane < 32)
            h1b[lane >> 1][192 + (lane & 1)] =
                (_Float16)((const float*)x_all[t + 1])[32 + lane];
        __syncthreads();
    }

    // ---- t = 19 peeled ----
    build(&h1b[0][0], accB);
    act(accA, &h0b[0][0][0], 0);
    sched_pattern();
    if (ht < 2)
        wout1(18, (ht == 0) ? &h0b[1][0][0] : &h1b[0][0]);
    __syncthreads();
    act(accB, &h1b[0][0], 4);
    __syncthreads();
    if (ht < 2)
        wout1(19, (ht == 0) ? &h0b[0][0][0] : &h1b[0][0]);
}

extern "C" void kernel_launch(void* const* d_in, const int* in_sizes, int n_in,
                              void* d_out, int out_size, void* d_ws, size_t ws_size,
                              hipStream_t stream) {
    const float* obs  = (const float*)d_in[0];
    const float* h0   = (const float*)d_in[1];
    const float* wih  = (const float*)d_in[2];
    const float* whh  = (const float*)d_in[3];
    const float* bih  = (const float*)d_in[4];
    const float* bhh  = (const float*)d_in[5];
    const float* wout = (const float*)d_in[6];
    const float* bout = (const float*)d_in[7];
    float* out = (float*)d_out;
    _Float16* frags = (_Float16*)d_ws;   // 313344 B used

    build_frags<<<(FR_TOTAL + 255) / 256, 256, 0, stream>>>(whh, wout, wih, bih, bhh, frags);
    lstm_fused_kernel<<<NSEQ / ROWS, 768, 0, stream>>>(obs, h0, bout, frags, out);
}